// Round 1
// baseline (760.603 us; speedup 1.0000x reference)
//
#include <hip/hip_runtime.h>
#include <stdint.h>

typedef unsigned short u16;
typedef __attribute__((ext_vector_type(8))) short bf16x8;   // 8 bf16 (4 VGPR)
typedef __attribute__((ext_vector_type(4))) short bf16x4;
typedef __attribute__((ext_vector_type(4))) float f32x4;

#define MFMA(A,B,C) __builtin_amdgcn_mfma_f32_16x16x32_bf16((A),(B),(C),0,0,0)

__device__ __forceinline__ u16 f2bf(float f) {
  uint32_t u = __float_as_uint(f);
  return (u16)((u + 0x7fffu + ((u >> 16) & 1u)) >> 16);   // RNE
}

__device__ __forceinline__ void async16(u16* lds, const u16* g) {
  __builtin_amdgcn_global_load_lds(
      (const __attribute__((address_space(1))) uint32_t*)g,
      (__attribute__((address_space(3))) uint32_t*)lds, 16, 0, 0);
}

// ---------------------------------------------------------------------------
// Weight prep: Wqkv fp32[384][1152] -> packed bf16 [48 kg][1152 n][8 k]
//              Wproj fp32[384][384] -> transposed bf16 WprojT[co][c]
// ---------------------------------------------------------------------------
__global__ void k_prep(const float* __restrict__ wqkv, const float* __restrict__ wproj,
                       u16* __restrict__ wqkvP, u16* __restrict__ wprojT)
{
  int i = blockIdx.x * 256 + threadIdx.x;
  if (i < 384 * 1152) {
    int kg = i / 9216; int rem = i - kg * 9216; int n = rem >> 3; int t = rem & 7;
    wqkvP[i] = (u16)f2bf(wqkv[(kg * 8 + t) * 1152 + n]);
  }
  if (i < 384 * 384) {
    int co = i / 384, c = i - co * 384;
    wprojT[i] = (u16)f2bf(wproj[c * 384 + co]);
  }
}

// ---------------------------------------------------------------------------
// K1: QKV = window_partition(x) @ Wqkv + b   (M=131072, N=1152, K=384)
// grid (mtiles, 3); ntile 0=Q, 1=K, 2=V. 512 thr = 8 waves (2m x 4n),
// BM=128, BN=384, BK=32, double-buffered LDS, 1 barrier per K-step.
// ---------------------------------------------------------------------------
__global__ __launch_bounds__(512, 2)
void k_qkv(const float* __restrict__ x, const u16* __restrict__ wp,
           const float* __restrict__ bqkv,
           u16* __restrict__ Qb, u16* __restrict__ Kbuf, u16* __restrict__ Vt)
{
  __shared__ alignas(16) u16 sA[2][128 * 40];     // padded stride 40 -> conflict-free
  __shared__ alignas(16) u16 sB[2][4 * 384 * 8];  // [kg][n][8] packed, linear for gload_lds
  const int tid = threadIdx.x;
  const int mtile = blockIdx.x, ntile = blockIdx.y;

  // A staging source (window-reordered fp32 row of x)
  const int ar = tid >> 2;            // tile row 0..127
  const int akq = (tid & 3) * 8;      // k sub-offset
  const float* xrow;
  {
    int m = mtile * 128 + ar;
    int win = m >> 6, ii = m & 63;
    int bb = win >> 8, wy = (win >> 4) & 15, wx = win & 15;
    int tok = (wy * 8 + (ii >> 3)) * 128 + wx * 8 + (ii & 7);
    xrow = x + (size_t)(bb * 16384 + tok) * 384 + akq;
  }
  // B staging pointers (3 x 16B per thread per step)
  const u16* gB[3]; int oB[3];
#pragma unroll
  for (int j = 0; j < 3; ++j) {
    int o = tid * 8 + j * 4096;
    int kgl = o / 3072, rem = o - kgl * 3072;
    gB[j] = wp + ntile * 3072 + kgl * 9216 + rem;
    oB[j] = o;
  }

  const int lane = tid & 63, l15 = lane & 15, l4 = lane >> 4;
  const int wid = tid >> 6, wm = wid >> 2, wn = wid & 3;
  int aidx[4], bidx[6];
#pragma unroll
  for (int mf = 0; mf < 4; ++mf) aidx[mf] = (wm * 64 + mf * 16 + l15) * 40 + l4 * 8;
#pragma unroll
  for (int nf = 0; nf < 6; ++nf) bidx[nf] = l4 * 3072 + (wn * 96 + nf * 16 + l15) * 8;

  f32x4 acc[4][6];
  const f32x4 z4 = {0.f, 0.f, 0.f, 0.f};
#pragma unroll
  for (int mf = 0; mf < 4; ++mf)
#pragma unroll
    for (int nf = 0; nf < 6; ++nf) acc[mf][nf] = z4;

  // prologue: stage tile 0
  {
    f32x4 a0 = *(const f32x4*)(xrow);
    f32x4 a1 = *(const f32x4*)(xrow + 4);
    bf16x8 w;
#pragma unroll
    for (int e = 0; e < 4; ++e) { w[e] = (short)f2bf(a0[e]); w[e + 4] = (short)f2bf(a1[e]); }
    *(bf16x8*)&sA[0][ar * 40 + akq] = w;
#pragma unroll
    for (int j = 0; j < 3; ++j) async16(&sB[0][oB[j]], gB[j]);
  }
  __syncthreads();

  for (int t = 0; t < 12; ++t) {
    const int cur = t & 1;
    f32x4 a0, a1;
    if (t < 11) {              // prefetch next A fragment (global -> regs)
      a0 = *(const f32x4*)(xrow + (t + 1) * 32);
      a1 = *(const f32x4*)(xrow + (t + 1) * 32 + 4);
    }
    // compute on current buffers
    bf16x8 af[4], bfr[6];
#pragma unroll
    for (int mf = 0; mf < 4; ++mf) af[mf] = *(const bf16x8*)&sA[cur][aidx[mf]];
#pragma unroll
    for (int nf = 0; nf < 6; ++nf) bfr[nf] = *(const bf16x8*)&sB[cur][bidx[nf]];
#pragma unroll
    for (int mf = 0; mf < 4; ++mf)
#pragma unroll
      for (int nf = 0; nf < 6; ++nf)
        acc[mf][nf] = MFMA(af[mf], bfr[nf], acc[mf][nf]);
    if (t < 11) {
      const int nxt = cur ^ 1;
      bf16x8 w;
#pragma unroll
      for (int e = 0; e < 4; ++e) { w[e] = (short)f2bf(a0[e]); w[e + 4] = (short)f2bf(a1[e]); }
      *(bf16x8*)&sA[nxt][ar * 40 + akq] = w;
#pragma unroll
      for (int j = 0; j < 3; ++j) async16(&sB[nxt][oB[j]], gB[j] + (size_t)(t + 1) * 36864);
    }
    __syncthreads();
  }

  // epilogue: bias + bf16 store
  float bv[6];
#pragma unroll
  for (int nf = 0; nf < 6; ++nf) bv[nf] = bqkv[ntile * 384 + wn * 96 + nf * 16 + l15];

  if (ntile < 2) {
    u16* dst = (ntile == 0) ? Qb : Kbuf;
#pragma unroll
    for (int mf = 0; mf < 4; ++mf) {
      size_t mbase = (size_t)(mtile * 128 + wm * 64 + mf * 16 + l4 * 4) * 384;
#pragma unroll
      for (int nf = 0; nf < 6; ++nf) {
        int c = wn * 96 + nf * 16 + l15;
#pragma unroll
        for (int e = 0; e < 4; ++e)
          dst[mbase + (size_t)e * 384 + c] = (u16)f2bf(acc[mf][nf][e] + bv[nf]);
      }
    }
  } else {  // V: store transposed Vt[win][c][key], 4 keys contiguous per lane
    int winv = mtile * 2 + wm;
#pragma unroll
    for (int mf = 0; mf < 4; ++mf) {
      int key = mf * 16 + l4 * 4;
#pragma unroll
      for (int nf = 0; nf < 6; ++nf) {
        int c = wn * 96 + nf * 16 + l15;
        bf16x4 pk;
#pragma unroll
        for (int e = 0; e < 4; ++e) pk[e] = (short)f2bf(acc[mf][nf][e] + bv[nf]);
        *(bf16x4*)&Vt[((size_t)winv * 384 + c) * 64 + key] = pk;
      }
    }
  }
}

// ---------------------------------------------------------------------------
// K2: per-window attention + fused proj.  1 window / 4-wave block.
// phase1: S = Q K^T (wave = 16 q-rows), in-reg softmax, P->LDS (swizzled)
// phase2: O-chunk = P V (wave = 96 c-cols), O->LDS bf16
// phase3: out^T-chunk = WprojT * O, scale 1/rowsum + bias, float4 store
// ---------------------------------------------------------------------------
__global__ __launch_bounds__(256, 2)
void k_attn(const u16* __restrict__ Qb, const u16* __restrict__ Kbuf,
            const u16* __restrict__ Vt, const u16* __restrict__ WpT,
            const float* __restrict__ bproj, float* __restrict__ out)
{
  __shared__ alignas(16) u16 sP[64 * 64];
  __shared__ alignas(16) u16 sO[64 * 384];
  __shared__ float sD[64];
  const int win = blockIdx.x;
  const int tid = threadIdx.x, wid = tid >> 6;
  const int lane = tid & 63, l15 = lane & 15, l4 = lane >> 4;
  const f32x4 z4 = {0.f, 0.f, 0.f, 0.f};

  // ---- phase 1: S = Q K^T for q-rows [wid*16, +16) ----
  f32x4 s[4];
#pragma unroll
  for (int nf = 0; nf < 4; ++nf) s[nf] = z4;
  const u16* qptr = Qb + (size_t)(win * 64 + wid * 16 + l15) * 384 + l4 * 8;
  const u16* kptr = Kbuf + (size_t)(win * 64 + l15) * 384 + l4 * 8;
#pragma unroll
  for (int cb = 0; cb < 384; cb += 32) {
    bf16x8 qa = *(const bf16x8*)(qptr + cb);
#pragma unroll
    for (int nf = 0; nf < 4; ++nf) {
      bf16x8 kf = *(const bf16x8*)(kptr + nf * 16 * 384 + cb);
      s[nf] = MFMA(qa, kf, s[nf]);
    }
  }
  // ---- softmax over 64 keys per q-row (reduce across 16-lane groups) ----
#pragma unroll
  for (int e = 0; e < 4; ++e) {
    float mx = fmaxf(fmaxf(s[0][e], s[1][e]), fmaxf(s[2][e], s[3][e]));
#pragma unroll
    for (int d = 1; d < 16; d <<= 1) mx = fmaxf(mx, __shfl_xor(mx, d, 64));
    float p0 = __expf(s[0][e] - mx), p1 = __expf(s[1][e] - mx);
    float p2 = __expf(s[2][e] - mx), p3 = __expf(s[3][e] - mx);
    float sum = (p0 + p1) + (p2 + p3);
#pragma unroll
    for (int d = 1; d < 16; d <<= 1) sum += __shfl_xor(sum, d, 64);
    int q = wid * 16 + l4 * 4 + e;
    int sw = (q & 7) << 3;
    sP[(q * 64 + l15) ^ sw]      = (u16)f2bf(p0);
    sP[(q * 64 + 16 + l15) ^ sw] = (u16)f2bf(p1);
    sP[(q * 64 + 32 + l15) ^ sw] = (u16)f2bf(p2);
    sP[(q * 64 + 48 + l15) ^ sw] = (u16)f2bf(p3);
    if (l15 == 0) sD[q] = sum;
  }
  __syncthreads();

  // ---- phase 2: O chunk (c in [wid*96,+96)) = P V ----
  bf16x8 pa[4][2];
#pragma unroll
  for (int mf = 0; mf < 4; ++mf)
#pragma unroll
    for (int ks = 0; ks < 2; ++ks) {
      int q = mf * 16 + l15;
      pa[mf][ks] = *(const bf16x8*)&sP[(q * 64 + ks * 32 + l4 * 8) ^ ((q & 7) << 3)];
    }
  f32x4 o[4][6];
#pragma unroll
  for (int mf = 0; mf < 4; ++mf)
#pragma unroll
    for (int nf = 0; nf < 6; ++nf) o[mf][nf] = z4;
  const u16* vptr = Vt + ((size_t)win * 384 + wid * 96 + l15) * 64 + l4 * 8;
#pragma unroll
  for (int nf = 0; nf < 6; ++nf)
#pragma unroll
    for (int ks = 0; ks < 2; ++ks) {
      bf16x8 vf = *(const bf16x8*)(vptr + nf * 16 * 64 + ks * 32);
#pragma unroll
      for (int mf = 0; mf < 4; ++mf)
        o[mf][nf] = MFMA(pa[mf][ks], vf, o[mf][nf]);
    }
#pragma unroll
  for (int mf = 0; mf < 4; ++mf)
#pragma unroll
    for (int nf = 0; nf < 6; ++nf)
#pragma unroll
      for (int e = 0; e < 4; ++e) {
        int q = mf * 16 + l4 * 4 + e;
        int c = wid * 96 + nf * 16 + l15;
        sO[(q * 384 + c) ^ ((q & 7) << 3)] = (u16)f2bf(o[mf][nf][e]);
      }
  __syncthreads();

  // ---- phase 3: out^T chunk (co in [wid*96,+96)) = WprojT * O ----
  f32x4 pacc[6][4];
#pragma unroll
  for (int mf = 0; mf < 6; ++mf)
#pragma unroll
    for (int nf = 0; nf < 4; ++nf) pacc[mf][nf] = z4;
  const u16* wptr = WpT + (size_t)(wid * 96 + l15) * 384 + l4 * 8;
#pragma unroll
  for (int cb = 0; cb < 384; cb += 32) {
    bf16x8 ob[4];
#pragma unroll
    for (int nf = 0; nf < 4; ++nf) {
      int q = nf * 16 + l15;
      ob[nf] = *(const bf16x8*)&sO[(q * 384 + cb + l4 * 8) ^ ((q & 7) << 3)];
    }
#pragma unroll
    for (int mf = 0; mf < 6; ++mf) {
      bf16x8 wf = *(const bf16x8*)(wptr + mf * 16 * 384 + cb);
#pragma unroll
      for (int nf = 0; nf < 4; ++nf)
        pacc[mf][nf] = MFMA(wf, ob[nf], pacc[mf][nf]);
    }
  }
  // epilogue: 1/rowsum scale + bias, direct float4 store in token order
  float rD[4];
#pragma unroll
  for (int nf = 0; nf < 4; ++nf) rD[nf] = 1.0f / sD[nf * 16 + l15];
  f32x4 bias[6];
#pragma unroll
  for (int mf = 0; mf < 6; ++mf) bias[mf] = *(const f32x4*)&bproj[wid * 96 + mf * 16 + l4 * 4];
  int bb = win >> 8, wy = (win >> 4) & 15, wx = win & 15;
#pragma unroll
  for (int nf = 0; nf < 4; ++nf) {
    int q = nf * 16 + l15;
    int tok = (wy * 8 + (q >> 3)) * 128 + wx * 8 + (q & 7);
    float* dst = out + (size_t)(bb * 16384 + tok) * 384 + wid * 96 + l4 * 4;
#pragma unroll
    for (int mf = 0; mf < 6; ++mf) {
      f32x4 v;
#pragma unroll
      for (int e = 0; e < 4; ++e) v[e] = pacc[mf][nf][e] * rD[nf] + bias[mf][e];
      *(f32x4*)(dst + mf * 16) = v;
    }
  }
}

// ---------------------------------------------------------------------------
extern "C" void kernel_launch(void* const* d_in, const int* in_sizes, int n_in,
                              void* d_out, int out_size, void* d_ws, size_t ws_size,
                              hipStream_t stream) {
  const float* x     = (const float*)d_in[0];
  const float* wqkv  = (const float*)d_in[1];
  const float* bqkv  = (const float*)d_in[2];
  const float* wproj = (const float*)d_in[3];
  const float* bproj = (const float*)d_in[4];
  float* out = (float*)d_out;
  const int Bn = in_sizes[0] / (16384 * 384);     // 8
  const size_t M = (size_t)Bn * 16384;            // 131072 rows

  u16* Qb     = (u16*)d_ws;
  u16* Kbuf   = Qb + M * 384;
  u16* Vt     = Kbuf + M * 384;
  u16* WqkvP  = Vt + M * 384;
  u16* WprojT = WqkvP + (size_t)384 * 1152;

  k_prep<<<dim3((384 * 1152 + 255) / 256), dim3(256), 0, stream>>>(wqkv, wproj, WqkvP, WprojT);
  k_qkv<<<dim3(Bn * 128, 3), dim3(512), 0, stream>>>(x, WqkvP, bqkv, Qb, Kbuf, Vt);
  k_attn<<<dim3(Bn * 256), dim3(256), 0, stream>>>(Qb, Kbuf, Vt, WprojT, bproj, out);
}

// Round 3
// 613.180 us; speedup vs baseline: 1.2404x; 1.2404x over previous
//
#include <hip/hip_runtime.h>
#include <stdint.h>

typedef unsigned short u16;
typedef __attribute__((ext_vector_type(8))) short bf16x8;   // 8 bf16 (4 VGPR)
typedef __attribute__((ext_vector_type(4))) short bf16x4;
typedef __attribute__((ext_vector_type(4))) float f32x4;

#define MFMA(A,B,C) __builtin_amdgcn_mfma_f32_16x16x32_bf16((A),(B),(C),0,0,0)

__device__ __forceinline__ u16 f2bf(float f) {
  uint32_t u = __float_as_uint(f);
  return (u16)((u + 0x7fffu + ((u >> 16) & 1u)) >> 16);   // RNE
}

__device__ __forceinline__ void async16(u16* lds, const u16* g) {
  __builtin_amdgcn_global_load_lds(
      (const __attribute__((address_space(1))) uint32_t*)g,
      (__attribute__((address_space(3))) uint32_t*)lds, 16, 0, 0);
}

// ---------------------------------------------------------------------------
// Weight prep: Wqkv fp32[384][1152] -> packed bf16 [48 kg][1152 n][8 k]
//              Wproj fp32[384][384] -> transposed bf16 WprojT[co][c]
// ---------------------------------------------------------------------------
__global__ void k_prep(const float* __restrict__ wqkv, const float* __restrict__ wproj,
                       u16* __restrict__ wqkvP, u16* __restrict__ wprojT)
{
  int i = blockIdx.x * 256 + threadIdx.x;
  if (i < 384 * 1152) {
    int kg = i / 9216; int rem = i - kg * 9216; int n = rem >> 3; int t = rem & 7;
    wqkvP[i] = (u16)f2bf(wqkv[(kg * 8 + t) * 1152 + n]);
  }
  if (i < 384 * 384) {
    int co = i / 384, c = i - co * 384;
    wprojT[i] = (u16)f2bf(wproj[c * 384 + co]);
  }
}

// ---------------------------------------------------------------------------
// K1: QKV for one window per block. 512 thr = 8 waves, each wave a 48-col
// slice. A tile (64x384) staged to LDS once (bf16, stride 392), then a
// BARRIER-FREE loop: 3 ntiles x 12 K-steps, B frags direct from L2.
// Q/K epilogue uses swapped-operand MFMA -> 8B row-major stores
// (K rows XOR-swizzled for k_attn's gload_lds staging). V stored transposed.
// ---------------------------------------------------------------------------
__global__ __launch_bounds__(512, 4)
void k_qkv(const float* __restrict__ x, const u16* __restrict__ wp,
           const float* __restrict__ bqkv,
           u16* __restrict__ Qb, u16* __restrict__ Kbuf, u16* __restrict__ Vt)
{
  __shared__ alignas(16) u16 sA[64 * 392];
  const int tid = threadIdx.x;
  const int win = blockIdx.x;
  const int bb = win >> 8, wy = (win >> 4) & 15, wx = win & 15;

  // ---- stage x window tile (fp32 -> bf16 LDS), once ----
  {
    int r = tid >> 3, c0 = (tid & 7) * 48;
    int tok = (wy * 8 + (r >> 3)) * 128 + wx * 8 + (r & 7);
    const float* src = x + (size_t)(bb * 16384 + tok) * 384 + c0;
    u16* dst = &sA[r * 392 + c0];
#pragma unroll
    for (int j = 0; j < 6; ++j) {
      f32x4 a0 = *(const f32x4*)(src + j * 8);
      f32x4 a1 = *(const f32x4*)(src + j * 8 + 4);
      bf16x8 w;
#pragma unroll
      for (int e = 0; e < 4; ++e) { w[e] = (short)f2bf(a0[e]); w[e + 4] = (short)f2bf(a1[e]); }
      *(bf16x8*)(dst + j * 8) = w;
    }
  }
  __syncthreads();

  const int lane = tid & 63, l15 = lane & 15, l4 = lane >> 4;
  const int wn = tid >> 6;                       // 8 waves = 8 col-slices of 48
  const u16* bB = wp + l4 * 9216 + (size_t)(wn * 48 + l15) * 8;
  const f32x4 z4 = {0.f, 0.f, 0.f, 0.f};

#pragma unroll
  for (int nt = 0; nt < 3; ++nt) {
    f32x4 acc[4][3];
#pragma unroll
    for (int mf = 0; mf < 4; ++mf)
#pragma unroll
      for (int nf = 0; nf < 3; ++nf) acc[mf][nf] = z4;
    const u16* bp = bB + nt * 3072;

    if (nt < 2) {  // Q, K : swapped operands (lane holds contiguous-c quad)
#pragma unroll
      for (int t = 0; t < 12; ++t) {
        bf16x8 af[4], bfr[3];
#pragma unroll
        for (int mf = 0; mf < 4; ++mf)
          af[mf] = *(const bf16x8*)&sA[(mf * 16 + l15) * 392 + t * 32 + l4 * 8];
#pragma unroll
        for (int nf = 0; nf < 3; ++nf)
          bfr[nf] = *(const bf16x8*)(bp + (size_t)t * 36864 + nf * 128);
#pragma unroll
        for (int mf = 0; mf < 4; ++mf)
#pragma unroll
          for (int nf = 0; nf < 3; ++nf)
            acc[mf][nf] = MFMA(bfr[nf], af[mf], acc[mf][nf]);
      }
      u16* dst = (nt == 0) ? Qb : Kbuf;
      f32x4 bias[3];
#pragma unroll
      for (int nf = 0; nf < 3; ++nf)
        bias[nf] = *(const f32x4*)&bqkv[nt * 384 + wn * 48 + nf * 16 + l4 * 4];
#pragma unroll
      for (int mf = 0; mf < 4; ++mf) {
        int row = mf * 16 + l15;
        char* rp = (char*)(dst + (size_t)(win * 64 + row) * 384);
        int sw = (nt == 1) ? ((row & 7) << 4) : 0;   // K rows XOR-swizzled
#pragma unroll
        for (int nf = 0; nf < 3; ++nf) {
          bf16x4 pk;
#pragma unroll
          for (int e = 0; e < 4; ++e) pk[e] = (short)f2bf(acc[mf][nf][e] + bias[nf][e]);
          *(bf16x4*)(rp + ((wn * 96 + nf * 32 + l4 * 8) ^ sw)) = pk;
        }
      }
    } else {       // V : normal order, store transposed Vt[win][c][key]
#pragma unroll
      for (int t = 0; t < 12; ++t) {
        bf16x8 af[4], bfr[3];
#pragma unroll
        for (int mf = 0; mf < 4; ++mf)
          af[mf] = *(const bf16x8*)&sA[(mf * 16 + l15) * 392 + t * 32 + l4 * 8];
#pragma unroll
        for (int nf = 0; nf < 3; ++nf)
          bfr[nf] = *(const bf16x8*)(bp + (size_t)t * 36864 + nf * 128);
#pragma unroll
        for (int mf = 0; mf < 4; ++mf)
#pragma unroll
          for (int nf = 0; nf < 3; ++nf)
            acc[mf][nf] = MFMA(af[mf], bfr[nf], acc[mf][nf]);
      }
      float bv[3];
#pragma unroll
      for (int nf = 0; nf < 3; ++nf) bv[nf] = bqkv[768 + wn * 48 + nf * 16 + l15];
#pragma unroll
      for (int mf = 0; mf < 4; ++mf) {
        int key = mf * 16 + l4 * 4;
#pragma unroll
        for (int nf = 0; nf < 3; ++nf) {
          int c = wn * 48 + nf * 16 + l15;
          bf16x4 pk;
#pragma unroll
          for (int e = 0; e < 4; ++e) pk[e] = (short)f2bf(acc[mf][nf][e] + bv[nf]);
          *(bf16x4*)&Vt[((size_t)win * 384 + c) * 64 + key] = pk;
        }
      }
    }
  }
}

// ---------------------------------------------------------------------------
// K2: per-window attention + fused proj. 256 thr = 4 waves, 2 blocks/CU.
// Q,V frags preloaded to regs; K async-staged to LDS (swizzled rows);
// swapped QK^T (q on l15) -> 2-shuffle softmax, 8B P/O stores;
// sO reuses the K LDS buffer (stride 392).
// ---------------------------------------------------------------------------
__global__ __launch_bounds__(256, 2)
void k_attn(const u16* __restrict__ Qb, const u16* __restrict__ Kbuf,
            const u16* __restrict__ Vt, const u16* __restrict__ WpT,
            const float* __restrict__ bproj, float* __restrict__ out)
{
  __shared__ alignas(16) u16 sKO[64 * 392];   // K (stride 384, swizzled) then O (stride 392)
  __shared__ alignas(16) u16 sP[64 * 64];
  __shared__ float sD[64];
  const int win = blockIdx.x;
  const int tid = threadIdx.x, wid = tid >> 6;
  const int lane = tid & 63, l15 = lane & 15, l4 = lane >> 4;
  const int swz = (l15 & 7) << 4;
  const f32x4 z4 = {0.f, 0.f, 0.f, 0.f};

  // ---- preload Q frags (Y-operand: l15 = q) and V frags; issue K staging ----
  bf16x8 qa[12];
  const u16* qp = Qb + (size_t)(win * 64 + wid * 16 + l15) * 384 + l4 * 8;
#pragma unroll
  for (int cb = 0; cb < 12; ++cb) qa[cb] = *(const bf16x8*)(qp + cb * 32);
  bf16x8 vfr[6][2];
  const u16* vp = Vt + ((size_t)win * 384 + wid * 96 + l15) * 64 + l4 * 8;
#pragma unroll
  for (int nf = 0; nf < 6; ++nf)
#pragma unroll
    for (int ks = 0; ks < 2; ++ks)
      vfr[nf][ks] = *(const bf16x8*)(vp + nf * 1024 + ks * 32);
  const u16* kg = Kbuf + (size_t)win * 64 * 384;
#pragma unroll
  for (int t = 0; t < 12; ++t)
    async16((u16*)sKO + (t * 256 + tid) * 8, kg + (size_t)(t * 256 + tid) * 8);
  __syncthreads();

  // ---- phase 1: S^T = K Q  (lane: q = wid*16+l15; e-dim: k) ----
  f32x4 s[4];
#pragma unroll
  for (int nf = 0; nf < 4; ++nf) s[nf] = z4;
#pragma unroll
  for (int cb = 0; cb < 12; ++cb) {
#pragma unroll
    for (int nf = 0; nf < 4; ++nf) {
      bf16x8 kf = *(const bf16x8*)((char*)sKO +
                    (((nf * 16 + l15) * 768 + cb * 64 + l4 * 16) ^ swz));
      s[nf] = MFMA(kf, qa[cb], s[nf]);
    }
  }
  // ---- softmax over 64 keys per q-row (16 local vals + 2 shuffles) ----
  float mx = s[0][0];
#pragma unroll
  for (int nf = 0; nf < 4; ++nf)
#pragma unroll
    for (int e = 0; e < 4; ++e) mx = fmaxf(mx, s[nf][e]);
  mx = fmaxf(mx, __shfl_xor(mx, 16, 64));
  mx = fmaxf(mx, __shfl_xor(mx, 32, 64));
  float p[4][4], sum = 0.f;
#pragma unroll
  for (int nf = 0; nf < 4; ++nf)
#pragma unroll
    for (int e = 0; e < 4; ++e) { p[nf][e] = __expf(s[nf][e] - mx); sum += p[nf][e]; }
  sum += __shfl_xor(sum, 16, 64);
  sum += __shfl_xor(sum, 32, 64);
  const int q1 = wid * 16 + l15;
  if (lane < 16) sD[q1] = sum;
#pragma unroll
  for (int nf = 0; nf < 4; ++nf) {
    bf16x4 pk;
#pragma unroll
    for (int e = 0; e < 4; ++e) pk[e] = (short)f2bf(p[nf][e]);
    *(bf16x4*)((char*)sP + ((q1 * 128 + nf * 32 + l4 * 8) ^ swz)) = pk;
  }
  __syncthreads();

  // ---- phase 2: O^T (c-rows) = V^T P^T ; write sO (stride 392) ----
  bf16x8 pa[4][2];
#pragma unroll
  for (int mf = 0; mf < 4; ++mf)
#pragma unroll
    for (int ks = 0; ks < 2; ++ks)
      pa[mf][ks] = *(const bf16x8*)((char*)sP +
                     (((mf * 16 + l15) * 128 + ks * 64 + l4 * 16) ^ swz));
  f32x4 o[6][4];
#pragma unroll
  for (int nf = 0; nf < 6; ++nf)
#pragma unroll
    for (int mf = 0; mf < 4; ++mf) o[nf][mf] = z4;
#pragma unroll
  for (int nf = 0; nf < 6; ++nf)
#pragma unroll
    for (int ks = 0; ks < 2; ++ks)
#pragma unroll
      for (int mf = 0; mf < 4; ++mf)
        o[nf][mf] = MFMA(vfr[nf][ks], pa[mf][ks], o[nf][mf]);
#pragma unroll
  for (int nf = 0; nf < 6; ++nf)
#pragma unroll
    for (int mf = 0; mf < 4; ++mf) {
      bf16x4 pk;
#pragma unroll
      for (int e = 0; e < 4; ++e) pk[e] = (short)f2bf(o[nf][mf][e]);
      *(bf16x4*)((char*)sKO + ((mf * 16 + l15) * 784 + wid * 192 + nf * 32 + l4 * 8)) = pk;
    }
  __syncthreads();

  // ---- phase 3: out^T chunk (co in [wid*96,+96)) = WprojT * O ----
  f32x4 pacc[6][4];
#pragma unroll
  for (int mf = 0; mf < 6; ++mf)
#pragma unroll
    for (int nf = 0; nf < 4; ++nf) pacc[mf][nf] = z4;
  const u16* wptr = WpT + (size_t)(wid * 96 + l15) * 384 + l4 * 8;
#pragma unroll
  for (int cb = 0; cb < 12; ++cb) {
    bf16x8 ob[4];
#pragma unroll
    for (int nf = 0; nf < 4; ++nf)
      ob[nf] = *(const bf16x8*)((char*)sKO + ((nf * 16 + l15) * 784 + cb * 64 + l4 * 16));
#pragma unroll
    for (int mf = 0; mf < 6; ++mf) {
      bf16x8 wf = *(const bf16x8*)(wptr + mf * 6144 + cb * 32);
#pragma unroll
      for (int nf = 0; nf < 4; ++nf)
        pacc[mf][nf] = MFMA(wf, ob[nf], pacc[mf][nf]);
    }
  }
  // epilogue: 1/rowsum scale + bias, direct float4 store in token order
  float rD[4];
#pragma unroll
  for (int nf = 0; nf < 4; ++nf) rD[nf] = 1.0f / sD[nf * 16 + l15];
  f32x4 bias[6];
#pragma unroll
  for (int mf = 0; mf < 6; ++mf) bias[mf] = *(const f32x4*)&bproj[wid * 96 + mf * 16 + l4 * 4];
  int bb = win >> 8, wy = (win >> 4) & 15, wx = win & 15;
#pragma unroll
  for (int nf = 0; nf < 4; ++nf) {
    int q = nf * 16 + l15;
    int tok = (wy * 8 + (q >> 3)) * 128 + wx * 8 + (q & 7);
    float* dst = out + (size_t)(bb * 16384 + tok) * 384 + wid * 96 + l4 * 4;
#pragma unroll
    for (int mf = 0; mf < 6; ++mf) {
      f32x4 v;
#pragma unroll
      for (int e = 0; e < 4; ++e) v[e] = pacc[mf][nf][e] * rD[nf] + bias[mf][e];
      *(f32x4*)(dst + mf * 16) = v;
    }
  }
}

// ---------------------------------------------------------------------------
extern "C" void kernel_launch(void* const* d_in, const int* in_sizes, int n_in,
                              void* d_out, int out_size, void* d_ws, size_t ws_size,
                              hipStream_t stream) {
  const float* x     = (const float*)d_in[0];
  const float* wqkv  = (const float*)d_in[1];
  const float* bqkv  = (const float*)d_in[2];
  const float* wproj = (const float*)d_in[3];
  const float* bproj = (const float*)d_in[4];
  float* out = (float*)d_out;
  const int Bn = in_sizes[0] / (16384 * 384);     // 8
  const size_t M = (size_t)Bn * 16384;            // 131072 rows
  const int nwin = Bn * 256;                      // 2048 windows

  u16* Qb     = (u16*)d_ws;
  u16* Kbuf   = Qb + M * 384;
  u16* Vt     = Kbuf + M * 384;
  u16* WqkvP  = Vt + M * 384;
  u16* WprojT = WqkvP + (size_t)384 * 1152;

  k_prep<<<dim3((384 * 1152 + 255) / 256), dim3(256), 0, stream>>>(wqkv, wproj, WqkvP, WprojT);
  k_qkv<<<dim3(nwin), dim3(512), 0, stream>>>(x, WqkvP, bqkv, Qb, Kbuf, Vt);
  k_attn<<<dim3(nwin), dim3(256), 0, stream>>>(Qb, Kbuf, Vt, WprojT, bproj, out);
}

// Round 4
// 562.441 us; speedup vs baseline: 1.3523x; 1.0902x over previous
//
#include <hip/hip_runtime.h>
#include <stdint.h>

typedef unsigned short u16;
typedef __attribute__((ext_vector_type(8))) short bf16x8;   // 8 bf16 (4 VGPR)
typedef __attribute__((ext_vector_type(4))) short bf16x4;
typedef __attribute__((ext_vector_type(4))) float f32x4;

#define MFMA(A,B,C) __builtin_amdgcn_mfma_f32_16x16x32_bf16((A),(B),(C),0,0,0)

__device__ __forceinline__ u16 f2bf(float f) {
  uint32_t u = __float_as_uint(f);
  return (u16)((u + 0x7fffu + ((u >> 16) & 1u)) >> 16);   // RNE
}

// ---------------------------------------------------------------------------
// Weight prep: Wqkv fp32[384][1152] -> packed bf16 [48 kg][1152 n][8 k]
//              Wproj fp32[384][384] -> transposed bf16 WprojT[co][c]
// ---------------------------------------------------------------------------
__global__ void k_prep(const float* __restrict__ wqkv, const float* __restrict__ wproj,
                       u16* __restrict__ wqkvP, u16* __restrict__ wprojT)
{
  int i = blockIdx.x * 256 + threadIdx.x;
  if (i < 384 * 1152) {
    int kg = i / 9216; int rem = i - kg * 9216; int n = rem >> 3; int t = rem & 7;
    wqkvP[i] = (u16)f2bf(wqkv[(kg * 8 + t) * 1152 + n]);
  }
  if (i < 384 * 384) {
    int co = i / 384, c = i - co * 384;
    wprojT[i] = (u16)f2bf(wproj[c * 384 + co]);
  }
}

// ---------------------------------------------------------------------------
// Fully fused: one window (64 tokens) per block, 512 thr = 8 waves.
// LDS map (dynamic, 147456 B):
//   [0,49152)      sX: x tile bf16, rows swizzled (^ (row&7)<<4), stride 768B
//                  -> after QKV: sP (8KB, stride 128B swizzled) + sD (f32[64] @8192)
//   [49152,98304)  sQ: Q bf16 swizzled -> after phase1: sO (swizzled, stride 768B)
//   [98304,147456) sK: K bf16 swizzled
// QKV: per wave a 48-col slice; Q&K fused t-loop (swapped-operand MFMA) with
// double-buffered L2 weight-frag prefetch; V kept in registers (layout feeds
// PV via two 8B P-reads per fragment -> no shuffles). Then attention + proj.
// ---------------------------------------------------------------------------
__global__ __launch_bounds__(512, 2)
void k_fused(const float* __restrict__ x, const u16* __restrict__ wp,
             const float* __restrict__ bqkv, const u16* __restrict__ WpT,
             const float* __restrict__ bproj, float* __restrict__ out)
{
  extern __shared__ char smem[];
  char* sX = smem;
  char* sQ = smem + 49152;
  char* sK = smem + 98304;
  float* sD = (float*)(smem + 8192);

  const int tid = threadIdx.x;
  const int win = blockIdx.x;
  const int bb = win >> 8, wy = (win >> 4) & 15, wx = win & 15;
  const int lane = tid & 63, l15 = lane & 15, l4 = lane >> 4;
  const int wn = tid >> 6;                 // wave id = col-slice (48 cols)
  const int swz = (l15 & 7) << 4;
  const f32x4 z4 = {0.f, 0.f, 0.f, 0.f};

  // ---- stage x window tile (fp32 -> bf16, swizzled rows) ----
  {
    int r = tid >> 3, c0 = (tid & 7) * 48;
    int tok = (wy * 8 + (r >> 3)) * 128 + wx * 8 + (r & 7);
    const float* src = x + (size_t)(bb * 16384 + tok) * 384 + c0;
    int rb = r * 768, sw = (r & 7) << 4;
#pragma unroll
    for (int j = 0; j < 6; ++j) {
      f32x4 a0 = *(const f32x4*)(src + j * 8);
      f32x4 a1 = *(const f32x4*)(src + j * 8 + 4);
      bf16x8 w;
#pragma unroll
      for (int e = 0; e < 4; ++e) { w[e] = (short)f2bf(a0[e]); w[e + 4] = (short)f2bf(a1[e]); }
      *(bf16x8*)(sX + ((rb + c0 * 2 + j * 16) ^ sw)) = w;
    }
  }

  const u16* bB = wp + l4 * 9216 + (size_t)(wn * 48 + l15) * 8;
  // prefetch t=0 Q/K weight frags before the barrier (L2, no LDS dependency)
  bf16x8 bq[3], bk[3], nbq[3], nbk[3];
#pragma unroll
  for (int nf = 0; nf < 3; ++nf) {
    bq[nf] = *(const bf16x8*)(bB + nf * 128);
    bk[nf] = *(const bf16x8*)(bB + 3072 + nf * 128);
  }
  __syncthreads();

  // ---- QKV part 1: Q and K, fused t-loop, swapped operands ----
  f32x4 aq[4][3], ak[4][3];
#pragma unroll
  for (int mf = 0; mf < 4; ++mf)
#pragma unroll
    for (int nf = 0; nf < 3; ++nf) { aq[mf][nf] = z4; ak[mf][nf] = z4; }
#pragma unroll
  for (int t = 0; t < 12; ++t) {
    if (t < 11) {
#pragma unroll
      for (int nf = 0; nf < 3; ++nf) {
        nbq[nf] = *(const bf16x8*)(bB + (size_t)(t + 1) * 36864 + nf * 128);
        nbk[nf] = *(const bf16x8*)(bB + (size_t)(t + 1) * 36864 + 3072 + nf * 128);
      }
    }
    bf16x8 af[4];
#pragma unroll
    for (int mf = 0; mf < 4; ++mf)
      af[mf] = *(const bf16x8*)(sX + (((mf * 16 + l15) * 768 + t * 64 + l4 * 16) ^ swz));
#pragma unroll
    for (int mf = 0; mf < 4; ++mf)
#pragma unroll
      for (int nf = 0; nf < 3; ++nf) {
        aq[mf][nf] = MFMA(bq[nf], af[mf], aq[mf][nf]);
        ak[mf][nf] = MFMA(bk[nf], af[mf], ak[mf][nf]);
      }
    if (t < 11) {
#pragma unroll
      for (int nf = 0; nf < 3; ++nf) { bq[nf] = nbq[nf]; bk[nf] = nbk[nf]; }
    }
  }
  // epilogue: bias + 8B swizzled stores to sQ / sK
  {
    f32x4 biasq[3], biask[3];
#pragma unroll
    for (int nf = 0; nf < 3; ++nf) {
      biasq[nf] = *(const f32x4*)&bqkv[wn * 48 + nf * 16 + l4 * 4];
      biask[nf] = *(const f32x4*)&bqkv[384 + wn * 48 + nf * 16 + l4 * 4];
    }
#pragma unroll
    for (int mf = 0; mf < 4; ++mf) {
      int rb = (mf * 16 + l15) * 768;
#pragma unroll
      for (int nf = 0; nf < 3; ++nf) {
        bf16x4 pq, pk_;
#pragma unroll
        for (int e = 0; e < 4; ++e) {
          pq[e]  = (short)f2bf(aq[mf][nf][e] + biasq[nf][e]);
          pk_[e] = (short)f2bf(ak[mf][nf][e] + biask[nf][e]);
        }
        *(bf16x4*)(sQ + ((rb + wn * 96 + nf * 32 + l4 * 8) ^ swz)) = pq;
        *(bf16x4*)(sK + ((rb + wn * 96 + nf * 32 + l4 * 8) ^ swz)) = pk_;
      }
    }
  }

  // ---- QKV part 2: V (normal operands) -> registers ----
  f32x4 av[4][3];
#pragma unroll
  for (int mf = 0; mf < 4; ++mf)
#pragma unroll
    for (int nf = 0; nf < 3; ++nf) av[mf][nf] = z4;
  {
    bf16x8 bv[3], nbv[3];
#pragma unroll
    for (int nf = 0; nf < 3; ++nf) bv[nf] = *(const bf16x8*)(bB + 6144 + nf * 128);
#pragma unroll
    for (int t = 0; t < 12; ++t) {
      if (t < 11) {
#pragma unroll
        for (int nf = 0; nf < 3; ++nf)
          nbv[nf] = *(const bf16x8*)(bB + (size_t)(t + 1) * 36864 + 6144 + nf * 128);
      }
      bf16x8 af[4];
#pragma unroll
      for (int mf = 0; mf < 4; ++mf)
        af[mf] = *(const bf16x8*)(sX + (((mf * 16 + l15) * 768 + t * 64 + l4 * 16) ^ swz));
#pragma unroll
      for (int mf = 0; mf < 4; ++mf)
#pragma unroll
        for (int nf = 0; nf < 3; ++nf)
          av[mf][nf] = MFMA(af[mf], bv[nf], av[mf][nf]);
      if (t < 11) {
#pragma unroll
        for (int nf = 0; nf < 3; ++nf) bv[nf] = nbv[nf];
      }
    }
  }
  // pack V into PV X-operand frags: vfr[nf][g] = keys {2g*16+l4*4+e, (2g+1)*16+l4*4+e}
  bf16x8 vfr[3][2];
  {
    float bvv[3];
#pragma unroll
    for (int nf = 0; nf < 3; ++nf) bvv[nf] = bqkv[768 + wn * 48 + nf * 16 + l15];
#pragma unroll
    for (int nf = 0; nf < 3; ++nf)
#pragma unroll
      for (int g = 0; g < 2; ++g) {
        bf16x8 w;
#pragma unroll
        for (int e = 0; e < 4; ++e) {
          w[e]     = (short)f2bf(av[2 * g][nf][e] + bvv[nf]);
          w[e + 4] = (short)f2bf(av[2 * g + 1][nf][e] + bvv[nf]);
        }
        vfr[nf][g] = w;
      }
  }
  __syncthreads();   // Q/K visible; x region now dead -> sP/sD

  // ---- phase 1: S^T = K Q for q-tile (wn>>1); even waves write P, D ----
  if ((wn & 1) == 0) {
    const int qt = wn >> 1;
    f32x4 s[4];
#pragma unroll
    for (int nf = 0; nf < 4; ++nf) s[nf] = z4;
#pragma unroll
    for (int cb = 0; cb < 12; ++cb) {
      bf16x8 qa = *(const bf16x8*)(sQ + (((qt * 16 + l15) * 768 + cb * 64 + l4 * 16) ^ swz));
#pragma unroll
      for (int nf = 0; nf < 4; ++nf) {
        bf16x8 kf = *(const bf16x8*)(sK + (((nf * 16 + l15) * 768 + cb * 64 + l4 * 16) ^ swz));
        s[nf] = MFMA(kf, qa, s[nf]);
      }
    }
    float mx = s[0][0];
#pragma unroll
    for (int nf = 0; nf < 4; ++nf)
#pragma unroll
      for (int e = 0; e < 4; ++e) mx = fmaxf(mx, s[nf][e]);
    mx = fmaxf(mx, __shfl_xor(mx, 16, 64));
    mx = fmaxf(mx, __shfl_xor(mx, 32, 64));
    float p[4][4], sum = 0.f;
#pragma unroll
    for (int nf = 0; nf < 4; ++nf)
#pragma unroll
      for (int e = 0; e < 4; ++e) { p[nf][e] = __expf(s[nf][e] - mx); sum += p[nf][e]; }
    sum += __shfl_xor(sum, 16, 64);
    sum += __shfl_xor(sum, 32, 64);
    const int q1 = qt * 16 + l15;
    if (l4 == 0) sD[q1] = sum;
#pragma unroll
    for (int nf = 0; nf < 4; ++nf) {
      bf16x4 w;
#pragma unroll
      for (int e = 0; e < 4; ++e) w[e] = (short)f2bf(p[nf][e]);
      *(bf16x4*)(sX + ((q1 * 128 + nf * 32 + l4 * 8) ^ swz)) = w;
    }
  }
  __syncthreads();   // P ready; sQ now dead -> sO

  // ---- phase 2: O^T (c-slice per wave) = V P^T, V from regs ----
  {
    bf16x8 pa[4][2];
#pragma unroll
    for (int mf = 0; mf < 4; ++mf) {
      int qb = (mf * 16 + l15) * 128;
#pragma unroll
      for (int g = 0; g < 2; ++g) {
        bf16x4 lo = *(const bf16x4*)(sX + ((qb + (2 * g) * 32 + l4 * 8) ^ swz));
        bf16x4 hi = *(const bf16x4*)(sX + ((qb + (2 * g + 1) * 32 + l4 * 8) ^ swz));
        bf16x8 w;
#pragma unroll
        for (int e = 0; e < 4; ++e) { w[e] = lo[e]; w[e + 4] = hi[e]; }
        pa[mf][g] = w;
      }
    }
    f32x4 o[3][4];
#pragma unroll
    for (int nf = 0; nf < 3; ++nf)
#pragma unroll
      for (int mf = 0; mf < 4; ++mf) o[nf][mf] = z4;
#pragma unroll
    for (int nf = 0; nf < 3; ++nf)
#pragma unroll
      for (int g = 0; g < 2; ++g)
#pragma unroll
        for (int mf = 0; mf < 4; ++mf)
          o[nf][mf] = MFMA(vfr[nf][g], pa[mf][g], o[nf][mf]);
#pragma unroll
    for (int mf = 0; mf < 4; ++mf) {
      int rb = (mf * 16 + l15) * 768;
#pragma unroll
      for (int nf = 0; nf < 3; ++nf) {
        bf16x4 w;
#pragma unroll
        for (int e = 0; e < 4; ++e) w[e] = (short)f2bf(o[nf][mf][e]);
        *(bf16x4*)(sQ + ((rb + wn * 96 + nf * 32 + l4 * 8) ^ swz)) = w;
      }
    }
  }
  __syncthreads();   // O ready

  // ---- phase 3: out^T (co-slice per wave) = WprojT O, scale + bias ----
  {
    f32x4 pacc[3][4];
#pragma unroll
    for (int mf = 0; mf < 3; ++mf)
#pragma unroll
      for (int nf = 0; nf < 4; ++nf) pacc[mf][nf] = z4;
    const u16* wptr = WpT + (size_t)(wn * 48 + l15) * 384 + l4 * 8;
    bf16x8 wf[3], nwf[3];
#pragma unroll
    for (int mf = 0; mf < 3; ++mf) wf[mf] = *(const bf16x8*)(wptr + mf * 6144);
#pragma unroll
    for (int cb = 0; cb < 12; ++cb) {
      if (cb < 11) {
#pragma unroll
        for (int mf = 0; mf < 3; ++mf)
          nwf[mf] = *(const bf16x8*)(wptr + mf * 6144 + (cb + 1) * 32);
      }
      bf16x8 ob[4];
#pragma unroll
      for (int nf = 0; nf < 4; ++nf)
        ob[nf] = *(const bf16x8*)(sQ + (((nf * 16 + l15) * 768 + cb * 64 + l4 * 16) ^ swz));
#pragma unroll
      for (int mf = 0; mf < 3; ++mf)
#pragma unroll
        for (int nf = 0; nf < 4; ++nf)
          pacc[mf][nf] = MFMA(wf[mf], ob[nf], pacc[mf][nf]);
      if (cb < 11) {
#pragma unroll
        for (int mf = 0; mf < 3; ++mf) wf[mf] = nwf[mf];
      }
    }
    float rD[4];
#pragma unroll
    for (int nf = 0; nf < 4; ++nf) rD[nf] = 1.0f / sD[nf * 16 + l15];
    f32x4 bias[3];
#pragma unroll
    for (int mf = 0; mf < 3; ++mf) bias[mf] = *(const f32x4*)&bproj[wn * 48 + mf * 16 + l4 * 4];
#pragma unroll
    for (int nf = 0; nf < 4; ++nf) {
      int q = nf * 16 + l15;
      int tok = (wy * 8 + (q >> 3)) * 128 + wx * 8 + (q & 7);
      float* dst = out + (size_t)(bb * 16384 + tok) * 384 + wn * 48 + l4 * 4;
#pragma unroll
      for (int mf = 0; mf < 3; ++mf) {
        f32x4 v;
#pragma unroll
        for (int e = 0; e < 4; ++e) v[e] = pacc[mf][nf][e] * rD[nf] + bias[mf][e];
        *(f32x4*)(dst + mf * 16) = v;
      }
    }
  }
}

// ---------------------------------------------------------------------------
extern "C" void kernel_launch(void* const* d_in, const int* in_sizes, int n_in,
                              void* d_out, int out_size, void* d_ws, size_t ws_size,
                              hipStream_t stream) {
  const float* x     = (const float*)d_in[0];
  const float* wqkv  = (const float*)d_in[1];
  const float* bqkv  = (const float*)d_in[2];
  const float* wproj = (const float*)d_in[3];
  const float* bproj = (const float*)d_in[4];
  float* out = (float*)d_out;
  const int Bn = in_sizes[0] / (16384 * 384);     // 8
  const int nwin = Bn * 256;                      // 2048 windows

  u16* WqkvP  = (u16*)d_ws;
  u16* WprojT = WqkvP + (size_t)384 * 1152;

  (void)hipFuncSetAttribute((const void*)k_fused,
                            hipFuncAttributeMaxDynamicSharedMemorySize, 147456);

  k_prep<<<dim3((384 * 1152 + 255) / 256), dim3(256), 0, stream>>>(wqkv, wproj, WqkvP, WprojT);
  k_fused<<<dim3(nwin), dim3(512), 147456, stream>>>(x, WqkvP, bqkv, WprojT, bproj, out);
}